// Round 16
// baseline (879.071 us; speedup 1.0000x reference)
//
#include <hip/hip_runtime.h>
#include <hip/hip_bf16.h>

#define QQ 128
#define CC 256
#define CH 96     // chunk rows (48 KB LDS tile -> 2 blocks/CU co-residency)

typedef __attribute__((ext_vector_type(8))) _Float16 half8;
typedef __attribute__((ext_vector_type(4))) _Float16 half4;
typedef __attribute__((ext_vector_type(4))) float f32x4;

__device__ __forceinline__ unsigned short f2h_bits(float f) {
    union { _Float16 h; unsigned short u; } cv;
    cv.h = (_Float16)f;
    return cv.u;
}

__device__ __forceinline__ half8 cvt8(f32x4 a, f32x4 b) {
    half8 h;
    h[0] = (_Float16)a.x; h[1] = (_Float16)a.y; h[2] = (_Float16)a.z; h[3] = (_Float16)a.w;
    h[4] = (_Float16)b.x; h[5] = (_Float16)b.y; h[6] = (_Float16)b.z; h[7] = (_Float16)b.w;
    return h;
}

// sum of v over all 256 threads; red is float[4] shared scratch
__device__ __forceinline__ float block_sum256(float v, float* red, int tid) {
#pragma unroll
    for (int off = 32; off > 0; off >>= 1)
        v += __shfl_down(v, off, 64);
    if ((tid & 63) == 0) red[tid >> 6] = v;
    __syncthreads();
    float s = red[0] + red[1] + red[2] + red[3];
    __syncthreads();
    return s;
}

// ---------------- K1: MLP head (LN -> L1 relu -> L2 relu -> L3) ----------------
__global__ __launch_bounds__(256) void k_mlp_head(
    const float* __restrict__ cc, const float* __restrict__ ln0w, const float* __restrict__ ln0b,
    const float* __restrict__ W1, const float* __restrict__ b1,
    const float* __restrict__ W2, const float* __restrict__ b2,
    const float* __restrict__ W3, const float* __restrict__ b3,
    unsigned short* __restrict__ Mh)
{
    const int q = blockIdx.x, t = threadIdx.x;
    __shared__ float xs[CC], ys[CC];
    __shared__ float red[4];

    float v = cc[q * CC + t];
    float s = block_sum256(v, red, t);
    float m = s * (1.0f / CC);
    float d = v - m;
    float s2 = block_sum256(d * d, red, t);
    float rstd = rsqrtf(s2 * (1.0f / CC) + 1e-5f);
    xs[t] = d * rstd * ln0w[t] + ln0b[t];
    __syncthreads();

    float acc = 0.f;
    {
        const float* w = W1 + t * CC;
#pragma unroll 8
        for (int k = 0; k < CC; k += 4) {
            f32x4 wv = *(const f32x4*)(w + k);
            acc += xs[k] * wv.x + xs[k + 1] * wv.y + xs[k + 2] * wv.z + xs[k + 3] * wv.w;
        }
    }
    ys[t] = fmaxf(acc + b1[t], 0.f);
    __syncthreads();

    acc = 0.f;
    {
        const float* w = W2 + t * CC;
#pragma unroll 8
        for (int k = 0; k < CC; k += 4) {
            f32x4 wv = *(const f32x4*)(w + k);
            acc += ys[k] * wv.x + ys[k + 1] * wv.y + ys[k + 2] * wv.z + ys[k + 3] * wv.w;
        }
    }
    float x2 = fmaxf(acc + b2[t], 0.f);
    __syncthreads();
    xs[t] = x2;
    __syncthreads();

    acc = 0.f;
    {
        const float* w = W3 + t * CC;
#pragma unroll 8
        for (int k = 0; k < CC; k += 4) {
            f32x4 wv = *(const f32x4*)(w + k);
            acc += xs[k] * wv.x + xs[k + 1] * wv.y + xs[k + 2] * wv.z + xs[k + 3] * wv.w;
        }
    }
    Mh[q * CC + t] = f2h_bits(acc + b3[t]);
}

// ---------------- K2: fused logits + argmax + segment-sum (v5) ---------------
// v5 = v4 with 96-row chunks: Ps 48 KB + aux ~10 KB = ~58 KB LDS -> 2 blocks
// of 512 thr co-resident per CU at any plausible LDS allocation granularity
// (v4's 78 KB blocked the 2nd allocation -> blocks serialized, occupancy 22.8%).
// launch_bounds(512,4) pins VGPR <= 128 (16 waves/CU needs it).
__global__ __launch_bounds__(512, 4) void k_fused(
    const float* __restrict__ P, const unsigned short* __restrict__ Mh,
    float* __restrict__ out, float* __restrict__ partial, int N, int ntiles)
{
    __shared__ __align__(16) unsigned short Ps[CH * CC];     // 48 KB, swizzled
    __shared__ float candv[8][CH];
    __shared__ int   candi[8][CH];
    __shared__ int   asg[128];          // only [0,CH) written; tail masked
    __shared__ int   wq[8][CH];         // per-wave row queues

    const int tid = threadIdx.x;
    const int w = tid >> 6, l = tid & 63;
    const int lr = l & 15, lg = l >> 4;
    const int myc0 = w << 4;                  // first cluster this wave owns
    char* const PsB = reinterpret_cast<char*>(Ps);

    // M fragments: bfrag[kk] = Mh[16w+lr][kk*32 + lg*8 .. +8]
    half8 bfrag[8];
#pragma unroll
    for (int kk = 0; kk < 8; ++kk)
        bfrag[kk] = *reinterpret_cast<const half8*>(Mh + (myc0 + lr) * CC + kk * 32 + lg * 8);

    // register bins: named (static indexing only). lane owns channels 4l..4l+3.
    f32x4 b0={0,0,0,0},b1=b0,b2=b0,b3=b0,b4=b0,b5=b0,b6=b0,b7=b0;
    f32x4 b8=b0,b9=b0,b10=b0,b11=b0,b12=b0,b13=b0,b14=b0,b15=b0;

    // staging regs: 6 tasks x 2 f32x4 (96 rows x 32 tasks/row / 512 thr)
    f32x4 sv[6][2];
    const int srow0 = tid >> 5;     // rows advance by 16 per it
    const int sck = tid & 31;

    const unsigned long long below = (1ull << l) - 1ull;

    // ---- prologue: stage first chunk ----
    int c = blockIdx.x;
    if (c < ntiles) {
        const int p0 = c * CH;
#pragma unroll
        for (int it = 0; it < 6; ++it) {
            int row = srow0 + (it << 4);
            int pr = min(p0 + row, N - 1);
            const float* src = P + (size_t)pr * CC + (sck << 3);
            sv[it][0] = *reinterpret_cast<const f32x4*>(src);
            sv[it][1] = *reinterpret_cast<const f32x4*>(src + 4);
        }
#pragma unroll
        for (int it = 0; it < 6; ++it) {
            int row = srow0 + (it << 4);
            int boff = (row << 9) + (((sck << 4)) ^ ((row & 7) << 4));
            *reinterpret_cast<half8*>(PsB + boff) = cvt8(sv[it][0], sv[it][1]);
        }
    }
    __syncthreads();

    for (; c < ntiles; ) {
        const int p0 = c * CH;
        const int cn = c + gridDim.x;
        const bool have_next = (cn < ntiles);

        // ---- issue next chunk's loads (in flight under compute) ----
        if (have_next) {
            const int np0 = cn * CH;
#pragma unroll
            for (int it = 0; it < 6; ++it) {
                int row = srow0 + (it << 4);
                int pr = min(np0 + row, N - 1);
                const float* src = P + (size_t)pr * CC + (sck << 3);
                sv[it][0] = *reinterpret_cast<const f32x4*>(src);
                sv[it][1] = *reinterpret_cast<const f32x4*>(src + 4);
            }
        }

        // ---- MFMA: rows 0..95 x clusters [16w,16w+16) ----
        const char* Pc = PsB;
        const int swz = (lr & 7) << 4;
        f32x4 acc0={0,0,0,0},acc1=acc0,acc2=acc0,acc3=acc0,acc4=acc0,acc5=acc0;
#define MFMA_RS(accv, rs)                                                              \
        {                                                                              \
            const char* rowp = Pc + ((rs * 16 + lr) << 9);                             \
            _Pragma("unroll")                                                          \
            for (int kk = 0; kk < 8; ++kk) {                                           \
                half8 a = *reinterpret_cast<const half8*>(rowp + (((kk << 6) + (lg << 4)) ^ swz)); \
                accv = __builtin_amdgcn_mfma_f32_16x16x32_f16(a, bfrag[kk], accv, 0, 0, 0); \
            }                                                                          \
        }
        MFMA_RS(acc0, 0) MFMA_RS(acc1, 1) MFMA_RS(acc2, 2)
        MFMA_RS(acc3, 3) MFMA_RS(acc4, 4) MFMA_RS(acc5, 5)
#undef MFMA_RS

        // ---- per-wave argmax (over this wave's 16 clusters) ----
#define ARGMAX_RS(accv, rs)                                                            \
        {                                                                              \
            _Pragma("unroll")                                                          \
            for (int j = 0; j < 4; ++j) {                                              \
                float bv = accv[j]; int bi = myc0 + lr;                                \
                _Pragma("unroll")                                                      \
                for (int msk = 1; msk < 16; msk <<= 1) {                               \
                    float ov = __shfl_xor(bv, msk, 64);                                \
                    int oi = __shfl_xor(bi, msk, 64);                                  \
                    if (ov > bv || (ov == bv && oi < bi)) { bv = ov; bi = oi; }        \
                }                                                                      \
                if (lr == 0) {                                                         \
                    int r = rs * 16 + (lg << 2) + j;                                   \
                    candv[w][r] = bv; candi[w][r] = bi;                                \
                }                                                                      \
            }                                                                          \
        }
        ARGMAX_RS(acc0, 0) ARGMAX_RS(acc1, 1) ARGMAX_RS(acc2, 2)
        ARGMAX_RS(acc3, 3) ARGMAX_RS(acc4, 4) ARGMAX_RS(acc5, 5)
#undef ARGMAX_RS
        __syncthreads();

        // ---- logits store + cross-wave combine ----
#define STORE_RS(accv, rs)                                                             \
        {                                                                              \
            _Pragma("unroll")                                                          \
            for (int j = 0; j < 4; ++j) {                                              \
                int r = rs * 16 + (lg << 2) + j;                                       \
                int p = p0 + r;                                                        \
                if (p < N) out[((size_t)p << 7) + myc0 + lr] = accv[j];                \
            }                                                                          \
        }
        STORE_RS(acc0, 0) STORE_RS(acc1, 1) STORE_RS(acc2, 2)
        STORE_RS(acc3, 3) STORE_RS(acc4, 4) STORE_RS(acc5, 5)
#undef STORE_RS
        if (tid < CH) {
            float bv = candv[0][tid]; int bi = candi[0][tid];
#pragma unroll
            for (int wv = 1; wv < 8; ++wv) {
                float ov = candv[wv][tid];
                if (ov > bv) { bv = ov; bi = candi[wv][tid]; } // ascending cluster blocks: strict > keeps lowest
            }
            asg[tid] = bi;
        }
        __syncthreads();

        // ---- segsum: ballot-compact this wave's rows, then pipelined walk ----
        {
            const int rmax = min(CH, N - p0);
            const int ra = asg[l];
            const int rb = (l < CH - 64) ? asg[l + 64] : 0;
            const bool ma = ((unsigned)(ra - myc0) < 16u) && (l < rmax);
            const bool mb = ((unsigned)(rb - myc0) < 16u) && (l + 64 < rmax);
            const unsigned long long mka = __ballot(ma);
            const unsigned long long mkb = __ballot(mb);
            const int cnta = __popcll(mka);
            if (ma) wq[w][__popcll(mka & below)] = (l << 8) | (ra - myc0);
            if (mb) wq[w][cnta + __popcll(mkb & below)] = ((l + 64) << 8) | (rb - myc0);
            const int qn = cnta + __popcll(mkb);

#define ACC_ONE(E)                                                                     \
            {                                                                          \
                const int r_ = (E) >> 8;                                               \
                const int ar_ = __builtin_amdgcn_readfirstlane((E) & 255);             \
                const int cb_ = (l << 3) ^ ((r_ & 7) << 4);                            \
                half4 hv_ = *reinterpret_cast<const half4*>(Pc + (r_ << 9) + cb_);     \
                f32x4 fv_;                                                             \
                fv_.x = (float)hv_[0]; fv_.y = (float)hv_[1];                          \
                fv_.z = (float)hv_[2]; fv_.w = (float)hv_[3];                          \
                if (ar_ < 8) {                                                         \
                    if (ar_ < 4) { if (ar_ < 2) { if (ar_ == 0) b0 += fv_; else b1 += fv_; } \
                                   else         { if (ar_ == 2) b2 += fv_; else b3 += fv_; } } \
                    else         { if (ar_ < 6) { if (ar_ == 4) b4 += fv_; else b5 += fv_; } \
                                   else         { if (ar_ == 6) b6 += fv_; else b7 += fv_; } } \
                } else {                                                               \
                    if (ar_ < 12){ if (ar_ < 10){ if (ar_ == 8) b8 += fv_; else b9 += fv_; } \
                                   else         { if (ar_ == 10) b10 += fv_; else b11 += fv_; } } \
                    else         { if (ar_ < 14){ if (ar_ == 12) b12 += fv_; else b13 += fv_; } \
                                   else         { if (ar_ == 14) b14 += fv_; else b15 += fv_; } } \
                }                                                                      \
            }
            int i = 0;
            for (; i + 4 <= qn; i += 4) {
                const int e0 = wq[w][i], e1 = wq[w][i + 1], e2 = wq[w][i + 2], e3 = wq[w][i + 3];
                ACC_ONE(e0) ACC_ONE(e1) ACC_ONE(e2) ACC_ONE(e3)
            }
            for (; i < qn; ++i) {
                const int e = wq[w][i];
                ACC_ONE(e)
            }
#undef ACC_ONE
        }
        __syncthreads();   // all reads of Ps done

        // ---- write prefetched regs into Ps ----
        if (have_next) {
#pragma unroll
            for (int it = 0; it < 6; ++it) {
                int row = srow0 + (it << 4);
                int boff = (row << 9) + (((sck << 4)) ^ ((row & 7) << 4));
                *reinterpret_cast<half8*>(PsB + boff) = cvt8(sv[it][0], sv[it][1]);
            }
            __syncthreads();
        }
        c = cn;
    }

    // ---- flush bins to partial[bid] ----
    {
        float* pb = partial + (size_t)blockIdx.x * (QQ * CC) + (size_t)myc0 * CC + (l << 2);
        f32x4 bb[16] = {b0,b1,b2,b3,b4,b5,b6,b7,b8,b9,b10,b11,b12,b13,b14,b15};
#pragma unroll
        for (int i = 0; i < 16; ++i)
            *reinterpret_cast<f32x4*>(pb + (size_t)i * CC) = bb[i];
    }
}

// ---------------- K4: reduce partials + bottleneck LN -> Wb -> LN, + residual --
__global__ __launch_bounds__(256) void k_bottleneck(
    const float* __restrict__ partial, int nparts,
    const float* __restrict__ lnb1w, const float* __restrict__ lnb1b,
    const float* __restrict__ Wb,
    const float* __restrict__ lnb2w, const float* __restrict__ lnb2b,
    const float* __restrict__ cc, float* __restrict__ out2)
{
    const int q = blockIdx.x, t = threadIdx.x;
    __shared__ float xs[CC];
    __shared__ float red[4];

    float v = 0.f;
    {
        const float* src = partial + (size_t)q * CC + t;
        int part = 0;
        for (; part + 7 < nparts; part += 8) {
            float s0 = src[(size_t)(part + 0) * (QQ * CC)];
            float s1 = src[(size_t)(part + 1) * (QQ * CC)];
            float s2 = src[(size_t)(part + 2) * (QQ * CC)];
            float s3 = src[(size_t)(part + 3) * (QQ * CC)];
            float s4 = src[(size_t)(part + 4) * (QQ * CC)];
            float s5 = src[(size_t)(part + 5) * (QQ * CC)];
            float s6 = src[(size_t)(part + 6) * (QQ * CC)];
            float s7 = src[(size_t)(part + 7) * (QQ * CC)];
            v += ((s0 + s1) + (s2 + s3)) + ((s4 + s5) + (s6 + s7));
        }
        for (; part < nparts; ++part)
            v += src[(size_t)part * (QQ * CC)];
    }

    float s = block_sum256(v, red, t);
    float m = s * (1.0f / CC);
    float d = v - m;
    float s2 = block_sum256(d * d, red, t);
    float rstd = rsqrtf(s2 * (1.0f / CC) + 1e-5f);
    xs[t] = d * rstd * lnb1w[t] + lnb1b[t];
    __syncthreads();

    float acc = 0.f;
    {
        const float* wp = Wb + t * CC;
#pragma unroll 8
        for (int k = 0; k < CC; k += 4) {
            f32x4 wv = *(const f32x4*)(wp + k);
            acc += xs[k] * wv.x + xs[k + 1] * wv.y + xs[k + 2] * wv.z + xs[k + 3] * wv.w;
        }
    }
    float zs = block_sum256(acc, red, t);
    float zm = zs * (1.0f / CC);
    float zd = acc - zm;
    float zs2 = block_sum256(zd * zd, red, t);
    float zr = rsqrtf(zs2 * (1.0f / CC) + 1e-5f);
    out2[q * CC + t] = cc[q * CC + t] + zd * zr * lnb2w[t] + lnb2b[t];
}

extern "C" void kernel_launch(void* const* d_in, const int* in_sizes, int n_in,
                              void* d_out, int out_size, void* d_ws, size_t ws_size,
                              hipStream_t stream) {
    const float* cc   = (const float*)d_in[0];
    const float* P    = (const float*)d_in[1];
    const float* ln0w = (const float*)d_in[2];
    const float* ln0b = (const float*)d_in[3];
    const float* W1   = (const float*)d_in[4];
    const float* b1   = (const float*)d_in[5];
    const float* W2   = (const float*)d_in[6];
    const float* b2   = (const float*)d_in[7];
    const float* W3   = (const float*)d_in[8];
    const float* b3   = (const float*)d_in[9];
    const float* lnb1w = (const float*)d_in[10];
    const float* lnb1b = (const float*)d_in[11];
    const float* Wb   = (const float*)d_in[12];
    const float* lnb2w = (const float*)d_in[13];
    const float* lnb2b = (const float*)d_in[14];

    const int N = in_sizes[1] / CC;

    char* ws = (char*)d_ws;
    unsigned short* Mh = (unsigned short*)ws;               // 65536 B
    float* partial = (float*)(ws + 65536);                  // nblk * 128 KB

    float* logits = (float*)d_out;                          // [N][128]
    float* out2 = (float*)d_out + (size_t)N * QQ;           // [128][256]

    // grid: 2 blocks per CU (512) if workspace allows, else 1 (256)
    int nblk = 512;
    const size_t part_bytes = (size_t)QQ * CC * sizeof(float);
    if (65536 + (size_t)nblk * part_bytes > ws_size) nblk = 256;

    k_mlp_head<<<QQ, 256, 0, stream>>>(cc, ln0w, ln0b, W1, b1, W2, b2, W3, b3, Mh);

    const int ntiles = (N + CH - 1) / CH;
    k_fused<<<nblk, 512, 0, stream>>>(P, Mh, logits, partial, N, ntiles);

    k_bottleneck<<<QQ, 256, 0, stream>>>(partial, nblk, lnb1w, lnb1b, Wb, lnb2w, lnb2b, cc, out2);
}

// Round 17
// 327.483 us; speedup vs baseline: 2.6843x; 2.6843x over previous
//
#include <hip/hip_runtime.h>
#include <hip/hip_bf16.h>

#define QQ 128
#define CC 256
#define GG 8      // clusters per group
#define NGRP 16   // 128/GG
#define HH 64     // range splits; segsum grid = NGRP*HH = 1024

typedef __attribute__((ext_vector_type(8))) _Float16 half8;
typedef __attribute__((ext_vector_type(4))) float f32x4;
typedef __attribute__((ext_vector_type(4))) int i32x4;

__device__ __forceinline__ unsigned short f2h_bits(float f) {
    union { _Float16 h; unsigned short u; } cv;
    cv.h = (_Float16)f;
    return cv.u;
}

__device__ __forceinline__ half8 cvt8(f32x4 a, f32x4 b) {
    half8 h;
    h[0] = (_Float16)a.x; h[1] = (_Float16)a.y; h[2] = (_Float16)a.z; h[3] = (_Float16)a.w;
    h[4] = (_Float16)b.x; h[5] = (_Float16)b.y; h[6] = (_Float16)b.z; h[7] = (_Float16)b.w;
    return h;
}

// sum of v over all 256 threads; red is float[4] shared scratch
__device__ __forceinline__ float block_sum256(float v, float* red, int tid) {
#pragma unroll
    for (int off = 32; off > 0; off >>= 1)
        v += __shfl_down(v, off, 64);
    if ((tid & 63) == 0) red[tid >> 6] = v;
    __syncthreads();
    float s = red[0] + red[1] + red[2] + red[3];
    __syncthreads();
    return s;
}

// ---------------- K1: MLP head (LN -> L1 relu -> L2 relu -> L3) ----------------
__global__ __launch_bounds__(256) void k_mlp_head(
    const float* __restrict__ cc, const float* __restrict__ ln0w, const float* __restrict__ ln0b,
    const float* __restrict__ W1, const float* __restrict__ b1,
    const float* __restrict__ W2, const float* __restrict__ b2,
    const float* __restrict__ W3, const float* __restrict__ b3,
    unsigned short* __restrict__ Mh)
{
    const int q = blockIdx.x, t = threadIdx.x;
    __shared__ float xs[CC], ys[CC];
    __shared__ float red[4];

    float v = cc[q * CC + t];
    float s = block_sum256(v, red, t);
    float m = s * (1.0f / CC);
    float d = v - m;
    float s2 = block_sum256(d * d, red, t);
    float rstd = rsqrtf(s2 * (1.0f / CC) + 1e-5f);
    xs[t] = d * rstd * ln0w[t] + ln0b[t];
    __syncthreads();

    float acc = 0.f;
    {
        const float* w = W1 + t * CC;
#pragma unroll 8
        for (int k = 0; k < CC; k += 4) {
            f32x4 wv = *(const f32x4*)(w + k);
            acc += xs[k] * wv.x + xs[k + 1] * wv.y + xs[k + 2] * wv.z + xs[k + 3] * wv.w;
        }
    }
    ys[t] = fmaxf(acc + b1[t], 0.f);
    __syncthreads();

    acc = 0.f;
    {
        const float* w = W2 + t * CC;
#pragma unroll 8
        for (int k = 0; k < CC; k += 4) {
            f32x4 wv = *(const f32x4*)(w + k);
            acc += ys[k] * wv.x + ys[k + 1] * wv.y + ys[k + 2] * wv.z + ys[k + 3] * wv.w;
        }
    }
    float x2 = fmaxf(acc + b2[t], 0.f);
    __syncthreads();
    xs[t] = x2;
    __syncthreads();

    acc = 0.f;
    {
        const float* w = W3 + t * CC;
#pragma unroll 8
        for (int k = 0; k < CC; k += 4) {
            f32x4 wv = *(const f32x4*)(w + k);
            acc += xs[k] * wv.x + xs[k + 1] * wv.y + xs[k + 2] * wv.z + xs[k + 3] * wv.w;
        }
    }
    Mh[q * CC + t] = f2h_bits(acc + b3[t]);
}

// ---------------- K2: logits = P @ M^T via f16 MFMA, + argmax ----------------
// v4 (round-8/10, measured-good): A-fragments straight from global (nontemporal),
// M in LDS (64 KB, staged once), epilogue LDS-transpose -> vector NT stores.
// 512 thr / 8 waves / 256 rows per block -> 2 blocks/CU, no K-loop barriers.
__global__ __launch_bounds__(512) void k_logits(
    const float* __restrict__ P, const unsigned short* __restrict__ Mh,
    float* __restrict__ out, int* __restrict__ assign, int N)
{
    __shared__ __align__(16) unsigned short Ms[QQ * CC]; // 64 KB, swizzled
    __shared__ __align__(16) float eps[8][4][128];       // 16 KB, wave-private transpose slots
    const int tid = threadIdx.x;
    const int p0 = blockIdx.x << 8;
    const int w = tid >> 6, l = tid & 63;
    const int lr = l & 15, lg = l >> 4;

    // stage M full (f16, swizzled): 4096 chunks of 16 B over 512 threads
#pragma unroll
    for (int it = 0; it < 8; ++it) {
        int i = tid + (it << 9);
        int row = i >> 5, ck = i & 31;
        uint4 vd = *(reinterpret_cast<const uint4*>(Mh + (row << 8)) + ck);
        int boff = (row << 9) + ((ck << 4) ^ ((row & 7) << 4));
        *reinterpret_cast<uint4*>(reinterpret_cast<char*>(Ms) + boff) = vd;
    }
    __syncthreads();

    f32x4 acc[2][8];
#pragma unroll
    for (int i = 0; i < 2; ++i)
#pragma unroll
        for (int j = 0; j < 8; ++j) acc[i][j] = (f32x4){0.f, 0.f, 0.f, 0.f};

    const char* MsB = reinterpret_cast<const char*>(Ms);
    const int sw0 = (lr & 7) << 4;
    const int kf = lg << 3; // f32 k-offset of this lane's 8-elem chunk

    // A source rows (clamped; rows >= N produce discarded C rows)
    const int ra0 = p0 + (w << 5) + lr;
    const int ra1 = ra0 + 16;
    const float* arow0 = P + (size_t)min(ra0, N - 1) * CC + kf;
    const float* arow1 = P + (size_t)min(ra1, N - 1) * CC + kf;

#pragma unroll
    for (int kk = 0; kk < 8; ++kk) {
        const float* pved0 = arow0 + (kk << 5);
        const float* pved1 = arow1 + (kk << 5);
        f32x4 a0lo = __builtin_nontemporal_load(reinterpret_cast<const f32x4*>(pved0));
        f32x4 a0hi = __builtin_nontemporal_load(reinterpret_cast<const f32x4*>(pved0 + 4));
        f32x4 a1lo = __builtin_nontemporal_load(reinterpret_cast<const f32x4*>(pved1));
        f32x4 a1hi = __builtin_nontemporal_load(reinterpret_cast<const f32x4*>(pved1 + 4));
        half8 a0 = cvt8(a0lo, a0hi);
        half8 a1 = cvt8(a1lo, a1hi);
        const int bk = (kk << 6) + (lg << 4);
#pragma unroll
        for (int ct = 0; ct < 8; ++ct) {
            const int rb = (ct << 4) + lr;
            half8 bb = *reinterpret_cast<const half8*>(MsB + (rb << 9) + (bk ^ sw0));
            acc[0][ct] = __builtin_amdgcn_mfma_f32_16x16x32_f16(a0, bb, acc[0][ct], 0, 0, 0);
            acc[1][ct] = __builtin_amdgcn_mfma_f32_16x16x32_f16(a1, bb, acc[1][ct], 0, 0, 0);
        }
    }

    // epilogue: argmax on registers, then LDS transpose -> vector stores.
    // C/D layout: col = ct*16 + lr, row = (w<<5) + rt*16 + lg*4 + j.
    float* myeps = &eps[w][0][0];
#pragma unroll
    for (int rt = 0; rt < 2; ++rt) {
#pragma unroll
        for (int j = 0; j < 4; ++j) {
            // argmax over this lane's 8 cols, then 16-lane reduce
            float bv = -3.402823e38f; int bi = 0;
#pragma unroll
            for (int ct = 0; ct < 8; ++ct) {
                float vv = acc[rt][ct][j];
                int cidx = (ct << 4) + lr;
                if (vv > bv) { bv = vv; bi = cidx; }
                myeps[(lg << 7) + cidx] = vv;   // transpose slot [lg][cidx]
            }
#pragma unroll
            for (int msk = 1; msk < 16; msk <<= 1) {
                float ov = __shfl_xor(bv, msk, 64);
                int oi = __shfl_xor(bi, msk, 64);
                if (ov > bv || (ov == bv && oi < bi)) { bv = ov; bi = oi; }
            }
            {
                const int rowm = (w << 5) + (rt << 4) + (lg << 2) + j;
                const int pm = p0 + rowm;
                if (lr == 0 && pm < N) assign[pm] = bi;
            }
            // read back row-major: lane l -> row (l>>4), cols (l&15)*8..+7
            f32x4 v0 = *reinterpret_cast<const f32x4*>(&myeps[((l >> 4) << 7) + ((l & 15) << 3)]);
            f32x4 v1 = *reinterpret_cast<const f32x4*>(&myeps[((l >> 4) << 7) + ((l & 15) << 3) + 4]);
            const int row = (w << 5) + (rt << 4) + ((l >> 4) << 2) + j;
            const int p = p0 + row;
            if (p < N) {
                float* dst = out + ((size_t)p << 7) + ((l & 15) << 3);
                __builtin_nontemporal_store(v0, reinterpret_cast<f32x4*>(dst));
                __builtin_nontemporal_store(v1, reinterpret_cast<f32x4*>(dst + 4));
            }
        }
    }
}

// ---------------- K3: segment sum, cluster-major, register accumulators --------
// grid = NGRP*HH blocks. Block (g = bid&15, h = bid>>4) owns clusters
// [g*8, g*8+8). Waves ballot-compact matching indices into a wave-private LDS
// queue (no atomics), then walk the queue: whole wave loads one point row
// (f32x4/lane, 1 KB coalesced, nontemporal) and accumulates into registers
// selected by a scalarized branch. No LDS in the hot loop.
__global__ __launch_bounds__(256, 4) void k_segsum(
    const float* __restrict__ P, const int* __restrict__ assign,
    float* __restrict__ partial, int N)
{
    __shared__ __align__(16) float redbuf[4][GG][CC];   // 32 KB
    int* queue = reinterpret_cast<int*>(redbuf);        // first 16 KB aliased as 4x1024 ints

    const int t = threadIdx.x;
    const int w = t >> 6, l = t & 63;
    const int g = blockIdx.x & (NGRP - 1);
    const int h = blockIdx.x >> 4;
    const int g0 = g << 3;
    const int wl = (h << 2) + w;           // 0..4*HH-1: wave index within group
    const int qb = w << 10;                // per-wave queue base (1024 entries)

    f32x4 a0v = {0,0,0,0}, a1v = a0v, a2v = a0v, a3v = a0v;
    f32x4 a4v = a0v, a5v = a0v, a6v = a0v, a7v = a0v;

    const unsigned long long below = (1ull << l) - 1ull;
    const int nchunks = (N + 1023) >> 10;
    const int stride = 4 * HH;

    if (wl < nchunks) {
    // reverse order: harvest L3-resident tail of P left by k_logits
    for (int c = wl + ((nchunks - 1 - wl) / stride) * stride; c >= 0; c -= stride) {
        const int cs = c << 10;
        const int ce = min(cs + 1024, N);
        int tail = 0;

        // ---- scan + compact (4 steps x 256 points) ----
#pragma unroll
        for (int s = 0; s < 4; ++s) {
            const int ib = cs + (s << 8) + (l << 2);
            i32x4 av = *reinterpret_cast<const i32x4*>(assign + ib); // may read past N within ws: masked below
#pragma unroll
            for (int j = 0; j < 4; ++j) {
                const int idx = ib + j;
                const int aj = av[j];
                const unsigned ci = (unsigned)(aj - g0);
                const bool m = (ci < (unsigned)GG) && (idx < ce);
                const unsigned long long mask = __ballot(m);
                const int pos = tail + __popcll(mask & below);
                if (m) queue[qb + pos] = (idx << 3) | (int)ci;
                tail += __popcll(mask);
            }
        }

        // ---- walk queue: 8 rows per step, pipelined ----
        int i = 0;
        for (; i + 8 <= tail; i += 8) {
            int e[8]; f32x4 v[8];
#pragma unroll
            for (int k = 0; k < 8; ++k) e[k] = queue[qb + i + k];     // broadcast reads
#pragma unroll
            for (int k = 0; k < 8; ++k) {
                const int pp = e[k] >> 3;
                v[k] = __builtin_nontemporal_load(
                    reinterpret_cast<const f32x4*>(P + (size_t)pp * CC + (l << 2)));
            }
#pragma unroll
            for (int k = 0; k < 8; ++k) {
                const int ci = __builtin_amdgcn_readfirstlane(e[k] & 7);
                const f32x4 vk = v[k];
                if (ci == 0)      a0v += vk;
                else if (ci == 1) a1v += vk;
                else if (ci == 2) a2v += vk;
                else if (ci == 3) a3v += vk;
                else if (ci == 4) a4v += vk;
                else if (ci == 5) a5v += vk;
                else if (ci == 6) a6v += vk;
                else              a7v += vk;
            }
        }
        for (; i < tail; ++i) {
            const int e = queue[qb + i];
            const int pp = e >> 3;
            const f32x4 vk = __builtin_nontemporal_load(
                reinterpret_cast<const f32x4*>(P + (size_t)pp * CC + (l << 2)));
            const int ci = __builtin_amdgcn_readfirstlane(e & 7);
            if (ci == 0)      a0v += vk;
            else if (ci == 1) a1v += vk;
            else if (ci == 2) a2v += vk;
            else if (ci == 3) a3v += vk;
            else if (ci == 4) a4v += vk;
            else if (ci == 5) a5v += vk;
            else if (ci == 6) a6v += vk;
            else              a7v += vk;
        }
    }
    }

    // ---- cross-wave reduce (queue region is dead after this barrier) ----
    __syncthreads();
    {
        f32x4 av[GG] = {a0v, a1v, a2v, a3v, a4v, a5v, a6v, a7v};
#pragma unroll
        for (int ci = 0; ci < GG; ++ci)
            *reinterpret_cast<f32x4*>(&redbuf[w][ci][l << 2]) = av[ci];
    }
    __syncthreads();

    float* pout = partial + (((size_t)h * QQ) + g0) * CC;
#pragma unroll
    for (int ci = 0; ci < GG; ++ci) {
        float sm = redbuf[0][ci][t] + redbuf[1][ci][t] + redbuf[2][ci][t] + redbuf[3][ci][t];
        pout[(size_t)ci * CC + t] = sm;
    }
}

// ---------------- K4: reduce partials + bottleneck LN -> Wb -> LN, + residual --
__global__ __launch_bounds__(256) void k_bottleneck(
    const float* __restrict__ partial, int nparts,
    const float* __restrict__ lnb1w, const float* __restrict__ lnb1b,
    const float* __restrict__ Wb,
    const float* __restrict__ lnb2w, const float* __restrict__ lnb2b,
    const float* __restrict__ cc, float* __restrict__ out2)
{
    const int q = blockIdx.x, t = threadIdx.x;
    __shared__ float xs[CC];
    __shared__ float red[4];

    float v = 0.f;
    {
        const float* src = partial + (size_t)q * CC + t;
        int part = 0;
        for (; part + 7 < nparts; part += 8) {
            float s0 = src[(size_t)(part + 0) * (QQ * CC)];
            float s1 = src[(size_t)(part + 1) * (QQ * CC)];
            float s2 = src[(size_t)(part + 2) * (QQ * CC)];
            float s3 = src[(size_t)(part + 3) * (QQ * CC)];
            float s4 = src[(size_t)(part + 4) * (QQ * CC)];
            float s5 = src[(size_t)(part + 5) * (QQ * CC)];
            float s6 = src[(size_t)(part + 6) * (QQ * CC)];
            float s7 = src[(size_t)(part + 7) * (QQ * CC)];
            v += ((s0 + s1) + (s2 + s3)) + ((s4 + s5) + (s6 + s7));
        }
        for (; part < nparts; ++part)
            v += src[(size_t)part * (QQ * CC)];
    }

    float s = block_sum256(v, red, t);
    float m = s * (1.0f / CC);
    float d = v - m;
    float s2 = block_sum256(d * d, red, t);
    float rstd = rsqrtf(s2 * (1.0f / CC) + 1e-5f);
    xs[t] = d * rstd * lnb1w[t] + lnb1b[t];
    __syncthreads();

    float acc = 0.f;
    {
        const float* wp = Wb + t * CC;
#pragma unroll 8
        for (int k = 0; k < CC; k += 4) {
            f32x4 wv = *(const f32x4*)(wp + k);
            acc += xs[k] * wv.x + xs[k + 1] * wv.y + xs[k + 2] * wv.z + xs[k + 3] * wv.w;
        }
    }
    float zs = block_sum256(acc, red, t);
    float zm = zs * (1.0f / CC);
    float zd = acc - zm;
    float zs2 = block_sum256(zd * zd, red, t);
    float zr = rsqrtf(zs2 * (1.0f / CC) + 1e-5f);
    out2[q * CC + t] = cc[q * CC + t] + zd * zr * lnb2w[t] + lnb2b[t];
}

extern "C" void kernel_launch(void* const* d_in, const int* in_sizes, int n_in,
                              void* d_out, int out_size, void* d_ws, size_t ws_size,
                              hipStream_t stream) {
    const float* cc   = (const float*)d_in[0];
    const float* P    = (const float*)d_in[1];
    const float* ln0w = (const float*)d_in[2];
    const float* ln0b = (const float*)d_in[3];
    const float* W1   = (const float*)d_in[4];
    const float* b1   = (const float*)d_in[5];
    const float* W2   = (const float*)d_in[6];
    const float* b2   = (const float*)d_in[7];
    const float* W3   = (const float*)d_in[8];
    const float* b3   = (const float*)d_in[9];
    const float* lnb1w = (const float*)d_in[10];
    const float* lnb1b = (const float*)d_in[11];
    const float* Wb   = (const float*)d_in[12];
    const float* lnb2w = (const float*)d_in[13];
    const float* lnb2b = (const float*)d_in[14];

    const int N = in_sizes[1] / CC;

    char* ws = (char*)d_ws;
    unsigned short* Mh = (unsigned short*)ws;               // 65536 B
    size_t off = 65536;
    int* assign = (int*)(ws + off);                         // 4*N B
    off += ((size_t)4 * N + 4095) & ~(size_t)4095;          // partial MUST follow assign (scan tail reads past N)
    float* partial = (float*)(ws + off);                    // HH * 128 KB = 8 MB

    float* logits = (float*)d_out;                          // [N][128]
    float* out2 = (float*)d_out + (size_t)N * QQ;           // [128][256]

    k_mlp_head<<<QQ, 256, 0, stream>>>(cc, ln0w, ln0b, W1, b1, W2, b2, W3, b3, Mh);

    int nblk = (N + 255) >> 8;
    k_logits<<<nblk, 512, 0, stream>>>(P, Mh, logits, assign, N);

    k_segsum<<<NGRP * HH, 256, 0, stream>>>(P, assign, partial, N);

    k_bottleneck<<<QQ, 256, 0, stream>>>(partial, HH, lnb1w, lnb1b, Wb, lnb2w, lnb2b, cc, out2);
}

// Round 18
// 315.665 us; speedup vs baseline: 2.7848x; 1.0374x over previous
//
#include <hip/hip_runtime.h>
#include <hip/hip_bf16.h>

#define QQ 128
#define CC 256
#define GG 8      // clusters per group
#define NGRP 16   // 128/GG
#define HH 64     // range splits; segsum grid = NGRP*HH = 1024

typedef __attribute__((ext_vector_type(8))) _Float16 half8;
typedef __attribute__((ext_vector_type(4))) float f32x4;
typedef __attribute__((ext_vector_type(4))) int i32x4;

__device__ __forceinline__ unsigned short f2h_bits(float f) {
    union { _Float16 h; unsigned short u; } cv;
    cv.h = (_Float16)f;
    return cv.u;
}

__device__ __forceinline__ half8 cvt8(f32x4 a, f32x4 b) {
    half8 h;
    h[0] = (_Float16)a.x; h[1] = (_Float16)a.y; h[2] = (_Float16)a.z; h[3] = (_Float16)a.w;
    h[4] = (_Float16)b.x; h[5] = (_Float16)b.y; h[6] = (_Float16)b.z; h[7] = (_Float16)b.w;
    return h;
}

// sum of v over all 256 threads; red is float[4] shared scratch
__device__ __forceinline__ float block_sum256(float v, float* red, int tid) {
#pragma unroll
    for (int off = 32; off > 0; off >>= 1)
        v += __shfl_down(v, off, 64);
    if ((tid & 63) == 0) red[tid >> 6] = v;
    __syncthreads();
    float s = red[0] + red[1] + red[2] + red[3];
    __syncthreads();
    return s;
}

// ---------------- K1: MLP head (LN -> L1 relu -> L2 relu -> L3) ----------------
__global__ __launch_bounds__(256) void k_mlp_head(
    const float* __restrict__ cc, const float* __restrict__ ln0w, const float* __restrict__ ln0b,
    const float* __restrict__ W1, const float* __restrict__ b1,
    const float* __restrict__ W2, const float* __restrict__ b2,
    const float* __restrict__ W3, const float* __restrict__ b3,
    unsigned short* __restrict__ Mh)
{
    const int q = blockIdx.x, t = threadIdx.x;
    __shared__ float xs[CC], ys[CC];
    __shared__ float red[4];

    float v = cc[q * CC + t];
    float s = block_sum256(v, red, t);
    float m = s * (1.0f / CC);
    float d = v - m;
    float s2 = block_sum256(d * d, red, t);
    float rstd = rsqrtf(s2 * (1.0f / CC) + 1e-5f);
    xs[t] = d * rstd * ln0w[t] + ln0b[t];
    __syncthreads();

    float acc = 0.f;
    {
        const float* w = W1 + t * CC;
#pragma unroll 8
        for (int k = 0; k < CC; k += 4) {
            f32x4 wv = *(const f32x4*)(w + k);
            acc += xs[k] * wv.x + xs[k + 1] * wv.y + xs[k + 2] * wv.z + xs[k + 3] * wv.w;
        }
    }
    ys[t] = fmaxf(acc + b1[t], 0.f);
    __syncthreads();

    acc = 0.f;
    {
        const float* w = W2 + t * CC;
#pragma unroll 8
        for (int k = 0; k < CC; k += 4) {
            f32x4 wv = *(const f32x4*)(w + k);
            acc += ys[k] * wv.x + ys[k + 1] * wv.y + ys[k + 2] * wv.z + ys[k + 3] * wv.w;
        }
    }
    float x2 = fmaxf(acc + b2[t], 0.f);
    __syncthreads();
    xs[t] = x2;
    __syncthreads();

    acc = 0.f;
    {
        const float* w = W3 + t * CC;
#pragma unroll 8
        for (int k = 0; k < CC; k += 4) {
            f32x4 wv = *(const f32x4*)(w + k);
            acc += xs[k] * wv.x + xs[k + 1] * wv.y + xs[k + 2] * wv.z + xs[k + 3] * wv.w;
        }
    }
    Mh[q * CC + t] = f2h_bits(acc + b3[t]);
}

// ---------------- K2: logits = P @ M^T via f16 MFMA, + argmax ----------------
// v5: = v4 but A-loads are PLAIN (not nontemporal) so P lines are retained in
// L2/L3 for k_segsum's reverse-order harvest (the NT hint was defeating it).
// 512 thr / 8 waves / 256 rows per block -> 2 blocks/CU, no K-loop barriers.
__global__ __launch_bounds__(512) void k_logits(
    const float* __restrict__ P, const unsigned short* __restrict__ Mh,
    float* __restrict__ out, int* __restrict__ assign, int N)
{
    __shared__ __align__(16) unsigned short Ms[QQ * CC]; // 64 KB, swizzled
    __shared__ __align__(16) float eps[8][4][128];       // 16 KB, wave-private transpose slots
    const int tid = threadIdx.x;
    const int p0 = blockIdx.x << 8;
    const int w = tid >> 6, l = tid & 63;
    const int lr = l & 15, lg = l >> 4;

    // stage M full (f16, swizzled): 4096 chunks of 16 B over 512 threads
#pragma unroll
    for (int it = 0; it < 8; ++it) {
        int i = tid + (it << 9);
        int row = i >> 5, ck = i & 31;
        uint4 vd = *(reinterpret_cast<const uint4*>(Mh + (row << 8)) + ck);
        int boff = (row << 9) + ((ck << 4) ^ ((row & 7) << 4));
        *reinterpret_cast<uint4*>(reinterpret_cast<char*>(Ms) + boff) = vd;
    }
    __syncthreads();

    f32x4 acc[2][8];
#pragma unroll
    for (int i = 0; i < 2; ++i)
#pragma unroll
        for (int j = 0; j < 8; ++j) acc[i][j] = (f32x4){0.f, 0.f, 0.f, 0.f};

    const char* MsB = reinterpret_cast<const char*>(Ms);
    const int sw0 = (lr & 7) << 4;
    const int kf = lg << 3; // f32 k-offset of this lane's 8-elem chunk

    // A source rows (clamped; rows >= N produce discarded C rows)
    const int ra0 = p0 + (w << 5) + lr;
    const int ra1 = ra0 + 16;
    const float* arow0 = P + (size_t)min(ra0, N - 1) * CC + kf;
    const float* arow1 = P + (size_t)min(ra1, N - 1) * CC + kf;

#pragma unroll
    for (int kk = 0; kk < 8; ++kk) {
        const float* pved0 = arow0 + (kk << 5);
        const float* pved1 = arow1 + (kk << 5);
        f32x4 a0lo = *reinterpret_cast<const f32x4*>(pved0);
        f32x4 a0hi = *reinterpret_cast<const f32x4*>(pved0 + 4);
        f32x4 a1lo = *reinterpret_cast<const f32x4*>(pved1);
        f32x4 a1hi = *reinterpret_cast<const f32x4*>(pved1 + 4);
        half8 a0 = cvt8(a0lo, a0hi);
        half8 a1 = cvt8(a1lo, a1hi);
        const int bk = (kk << 6) + (lg << 4);
#pragma unroll
        for (int ct = 0; ct < 8; ++ct) {
            const int rb = (ct << 4) + lr;
            half8 bb = *reinterpret_cast<const half8*>(MsB + (rb << 9) + (bk ^ sw0));
            acc[0][ct] = __builtin_amdgcn_mfma_f32_16x16x32_f16(a0, bb, acc[0][ct], 0, 0, 0);
            acc[1][ct] = __builtin_amdgcn_mfma_f32_16x16x32_f16(a1, bb, acc[1][ct], 0, 0, 0);
        }
    }

    // epilogue: argmax on registers, then LDS transpose -> vector stores.
    // C/D layout: col = ct*16 + lr, row = (w<<5) + rt*16 + lg*4 + j.
    float* myeps = &eps[w][0][0];
#pragma unroll
    for (int rt = 0; rt < 2; ++rt) {
#pragma unroll
        for (int j = 0; j < 4; ++j) {
            // argmax over this lane's 8 cols, then 16-lane reduce
            float bv = -3.402823e38f; int bi = 0;
#pragma unroll
            for (int ct = 0; ct < 8; ++ct) {
                float vv = acc[rt][ct][j];
                int cidx = (ct << 4) + lr;
                if (vv > bv) { bv = vv; bi = cidx; }
                myeps[(lg << 7) + cidx] = vv;   // transpose slot [lg][cidx]
            }
#pragma unroll
            for (int msk = 1; msk < 16; msk <<= 1) {
                float ov = __shfl_xor(bv, msk, 64);
                int oi = __shfl_xor(bi, msk, 64);
                if (ov > bv || (ov == bv && oi < bi)) { bv = ov; bi = oi; }
            }
            {
                const int rowm = (w << 5) + (rt << 4) + (lg << 2) + j;
                const int pm = p0 + rowm;
                if (lr == 0 && pm < N) assign[pm] = bi;
            }
            // read back row-major: lane l -> row (l>>4), cols (l&15)*8..+7
            f32x4 v0 = *reinterpret_cast<const f32x4*>(&myeps[((l >> 4) << 7) + ((l & 15) << 3)]);
            f32x4 v1 = *reinterpret_cast<const f32x4*>(&myeps[((l >> 4) << 7) + ((l & 15) << 3) + 4]);
            const int row = (w << 5) + (rt << 4) + ((l >> 4) << 2) + j;
            const int p = p0 + row;
            if (p < N) {
                float* dst = out + ((size_t)p << 7) + ((l & 15) << 3);
                __builtin_nontemporal_store(v0, reinterpret_cast<f32x4*>(dst));
                __builtin_nontemporal_store(v1, reinterpret_cast<f32x4*>(dst + 4));
            }
        }
    }
}

// ---------------- K3: segment sum, cluster-major, register accumulators --------
// grid = NGRP*HH blocks. Block (g = bid&15, h = bid>>4) owns clusters
// [g*8, g*8+8). Waves ballot-compact matching indices into a wave-private LDS
// queue (no atomics), then walk the queue: whole wave loads one point row
// (f32x4/lane, 1 KB coalesced, nontemporal) and accumulates into registers
// selected by a scalarized branch. No LDS in the hot loop. Reverse chunk
// order harvests the L3-resident tail of P left by k_logits (plain loads).
__global__ __launch_bounds__(256, 4) void k_segsum(
    const float* __restrict__ P, const int* __restrict__ assign,
    float* __restrict__ partial, int N)
{
    __shared__ __align__(16) float redbuf[4][GG][CC];   // 32 KB
    int* queue = reinterpret_cast<int*>(redbuf);        // first 16 KB aliased as 4x1024 ints

    const int t = threadIdx.x;
    const int w = t >> 6, l = t & 63;
    const int g = blockIdx.x & (NGRP - 1);
    const int h = blockIdx.x >> 4;
    const int g0 = g << 3;
    const int wl = (h << 2) + w;           // 0..4*HH-1: wave index within group
    const int qb = w << 10;                // per-wave queue base (1024 entries)

    f32x4 a0v = {0,0,0,0}, a1v = a0v, a2v = a0v, a3v = a0v;
    f32x4 a4v = a0v, a5v = a0v, a6v = a0v, a7v = a0v;

    const unsigned long long below = (1ull << l) - 1ull;
    const int nchunks = (N + 1023) >> 10;
    const int stride = 4 * HH;

    if (wl < nchunks) {
    // reverse order: harvest L3-resident tail of P left by k_logits
    for (int c = wl + ((nchunks - 1 - wl) / stride) * stride; c >= 0; c -= stride) {
        const int cs = c << 10;
        const int ce = min(cs + 1024, N);
        int tail = 0;

        // ---- scan + compact (4 steps x 256 points) ----
#pragma unroll
        for (int s = 0; s < 4; ++s) {
            const int ib = cs + (s << 8) + (l << 2);
            i32x4 av = *reinterpret_cast<const i32x4*>(assign + ib); // may read past N within ws: masked below
#pragma unroll
            for (int j = 0; j < 4; ++j) {
                const int idx = ib + j;
                const int aj = av[j];
                const unsigned ci = (unsigned)(aj - g0);
                const bool m = (ci < (unsigned)GG) && (idx < ce);
                const unsigned long long mask = __ballot(m);
                const int pos = tail + __popcll(mask & below);
                if (m) queue[qb + pos] = (idx << 3) | (int)ci;
                tail += __popcll(mask);
            }
        }

        // ---- walk queue: 8 rows per step, pipelined ----
        int i = 0;
        for (; i + 8 <= tail; i += 8) {
            int e[8]; f32x4 v[8];
#pragma unroll
            for (int k = 0; k < 8; ++k) e[k] = queue[qb + i + k];     // broadcast reads
#pragma unroll
            for (int k = 0; k < 8; ++k) {
                const int pp = e[k] >> 3;
                v[k] = __builtin_nontemporal_load(
                    reinterpret_cast<const f32x4*>(P + (size_t)pp * CC + (l << 2)));
            }
#pragma unroll
            for (int k = 0; k < 8; ++k) {
                const int ci = __builtin_amdgcn_readfirstlane(e[k] & 7);
                const f32x4 vk = v[k];
                if (ci == 0)      a0v += vk;
                else if (ci == 1) a1v += vk;
                else if (ci == 2) a2v += vk;
                else if (ci == 3) a3v += vk;
                else if (ci == 4) a4v += vk;
                else if (ci == 5) a5v += vk;
                else if (ci == 6) a6v += vk;
                else              a7v += vk;
            }
        }
        for (; i < tail; ++i) {
            const int e = queue[qb + i];
            const int pp = e >> 3;
            const f32x4 vk = __builtin_nontemporal_load(
                reinterpret_cast<const f32x4*>(P + (size_t)pp * CC + (l << 2)));
            const int ci = __builtin_amdgcn_readfirstlane(e & 7);
            if (ci == 0)      a0v += vk;
            else if (ci == 1) a1v += vk;
            else if (ci == 2) a2v += vk;
            else if (ci == 3) a3v += vk;
            else if (ci == 4) a4v += vk;
            else if (ci == 5) a5v += vk;
            else if (ci == 6) a6v += vk;
            else              a7v += vk;
        }
    }
    }

    // ---- cross-wave reduce (queue region is dead after this barrier) ----
    __syncthreads();
    {
        f32x4 av[GG] = {a0v, a1v, a2v, a3v, a4v, a5v, a6v, a7v};
#pragma unroll
        for (int ci = 0; ci < GG; ++ci)
            *reinterpret_cast<f32x4*>(&redbuf[w][ci][l << 2]) = av[ci];
    }
    __syncthreads();

    float* pout = partial + (((size_t)h * QQ) + g0) * CC;
#pragma unroll
    for (int ci = 0; ci < GG; ++ci) {
        float sm = redbuf[0][ci][t] + redbuf[1][ci][t] + redbuf[2][ci][t] + redbuf[3][ci][t];
        pout[(size_t)ci * CC + t] = sm;
    }
}

// ---------------- K4: reduce partials + bottleneck LN -> Wb -> LN, + residual --
__global__ __launch_bounds__(256) void k_bottleneck(
    const float* __restrict__ partial, int nparts,
    const float* __restrict__ lnb1w, const float* __restrict__ lnb1b,
    const float* __restrict__ Wb,
    const float* __restrict__ lnb2w, const float* __restrict__ lnb2b,
    const float* __restrict__ cc, float* __restrict__ out2)
{
    const int q = blockIdx.x, t = threadIdx.x;
    __shared__ float xs[CC];
    __shared__ float red[4];

    float v = 0.f;
    {
        const float* src = partial + (size_t)q * CC + t;
        int part = 0;
        for (; part + 7 < nparts; part += 8) {
            float s0 = src[(size_t)(part + 0) * (QQ * CC)];
            float s1 = src[(size_t)(part + 1) * (QQ * CC)];
            float s2 = src[(size_t)(part + 2) * (QQ * CC)];
            float s3 = src[(size_t)(part + 3) * (QQ * CC)];
            float s4 = src[(size_t)(part + 4) * (QQ * CC)];
            float s5 = src[(size_t)(part + 5) * (QQ * CC)];
            float s6 = src[(size_t)(part + 6) * (QQ * CC)];
            float s7 = src[(size_t)(part + 7) * (QQ * CC)];
            v += ((s0 + s1) + (s2 + s3)) + ((s4 + s5) + (s6 + s7));
        }
        for (; part < nparts; ++part)
            v += src[(size_t)part * (QQ * CC)];
    }

    float s = block_sum256(v, red, t);
    float m = s * (1.0f / CC);
    float d = v - m;
    float s2 = block_sum256(d * d, red, t);
    float rstd = rsqrtf(s2 * (1.0f / CC) + 1e-5f);
    xs[t] = d * rstd * lnb1w[t] + lnb1b[t];
    __syncthreads();

    float acc = 0.f;
    {
        const float* wp = Wb + t * CC;
#pragma unroll 8
        for (int k = 0; k < CC; k += 4) {
            f32x4 wv = *(const f32x4*)(wp + k);
            acc += xs[k] * wv.x + xs[k + 1] * wv.y + xs[k + 2] * wv.z + xs[k + 3] * wv.w;
        }
    }
    float zs = block_sum256(acc, red, t);
    float zm = zs * (1.0f / CC);
    float zd = acc - zm;
    float zs2 = block_sum256(zd * zd, red, t);
    float zr = rsqrtf(zs2 * (1.0f / CC) + 1e-5f);
    out2[q * CC + t] = cc[q * CC + t] + zd * zr * lnb2w[t] + lnb2b[t];
}

extern "C" void kernel_launch(void* const* d_in, const int* in_sizes, int n_in,
                              void* d_out, int out_size, void* d_ws, size_t ws_size,
                              hipStream_t stream) {
    const float* cc   = (const float*)d_in[0];
    const float* P    = (const float*)d_in[1];
    const float* ln0w = (const float*)d_in[2];
    const float* ln0b = (const float*)d_in[3];
    const float* W1   = (const float*)d_in[4];
    const float* b1   = (const float*)d_in[5];
    const float* W2   = (const float*)d_in[6];
    const float* b2   = (const float*)d_in[7];
    const float* W3   = (const float*)d_in[8];
    const float* b3   = (const float*)d_in[9];
    const float* lnb1w = (const float*)d_in[10];
    const float* lnb1b = (const float*)d_in[11];
    const float* Wb   = (const float*)d_in[12];
    const float* lnb2w = (const float*)d_in[13];
    const float* lnb2b = (const float*)d_in[14];

    const int N = in_sizes[1] / CC;

    char* ws = (char*)d_ws;
    unsigned short* Mh = (unsigned short*)ws;               // 65536 B
    size_t off = 65536;
    int* assign = (int*)(ws + off);                         // 4*N B
    off += ((size_t)4 * N + 4095) & ~(size_t)4095;          // partial MUST follow assign (scan tail reads past N)
    float* partial = (float*)(ws + off);                    // HH * 128 KB = 8 MB

    float* logits = (float*)d_out;                          // [N][128]
    float* out2 = (float*)d_out + (size_t)N * QQ;           // [128][256]

    k_mlp_head<<<QQ, 256, 0, stream>>>(cc, ln0w, ln0b, W1, b1, W2, b2, W3, b3, Mh);

    int nblk = (N + 255) >> 8;
    k_logits<<<nblk, 512, 0, stream>>>(P, Mh, logits, assign, N);

    k_segsum<<<NGRP * HH, 256, 0, stream>>>(P, assign, partial, N);

    k_bottleneck<<<QQ, 256, 0, stream>>>(partial, HH, lnb1w, lnb1b, Wb, lnb2w, lnb2b, cc, out2);
}